// Round 8
// baseline (256.283 us; speedup 1.0000x reference)
//
#include <hip/hip_runtime.h>
#include <hip/hip_bf16.h>

#define Bn 8
#define Nn 4096
#define Cn 1024
#define Dn 512
#define Mn 64

typedef __hip_bfloat16 bf16;
typedef __attribute__((ext_vector_type(8))) short short8;
typedef __attribute__((ext_vector_type(4))) short short4x;
typedef __attribute__((ext_vector_type(4))) float f32x4;

#define MFMA16(a, b, c) __builtin_amdgcn_mfma_f32_16x16x32_bf16((a), (b), (c), 0, 0, 0)

__device__ inline short bfbits(float f) {
  union { bf16 b; short s; } u;
  u.b = __float2bfloat16(f);
  return u.s;
}

// async global->LDS, 16B per lane; dest = wave-uniform base + lane*16 (HW)
__device__ __forceinline__ void gl_lds16(const bf16* g, short* l) {
  __builtin_amdgcn_global_load_lds(
      (const __attribute__((address_space(1))) void*)g,
      (__attribute__((address_space(3))) void*)l, 16, 0, 0);
}

// ---------------------------------------------------------------------------
// K0: V[m][c] = sum_d av[m][d]*W[d][c]; written in K1's swizzled LDS image:
// short idx = chunk*4096 + m*64 + (kk ^ ((m&7)<<3)),  chunk=c>>6, kk=c&63.
// (XOR on bits>=3 of a 64-short row -> b128 reads conflict-free in K1.)
// c0[m] = av[m,:].bias.  grid (Mn, Cn/64) = 1024 blocks, block 256.
// ---------------------------------------------------------------------------
__global__ __launch_bounds__(256) void prep_kernel(
    const float* __restrict__ W, const float* __restrict__ bias,
    const float* __restrict__ av, bf16* __restrict__ VgH,
    bf16* __restrict__ VgL, float* __restrict__ c0) {
  const int m = blockIdx.x;
  const int t = threadIdx.x;
  const int cl = t & 63, dg = t >> 6;
  const int c = blockIdx.y * 64 + cl;
  const float* wp = W + (size_t)(dg * 128) * Cn + c;
  const float* ap = av + m * Dn + dg * 128;
  float a0 = 0.f, a1 = 0.f, a2 = 0.f, a3 = 0.f;
#pragma unroll 8
  for (int i = 0; i < 128; i += 4) {
    a0 = fmaf(ap[i + 0], wp[(size_t)(i + 0) * Cn], a0);
    a1 = fmaf(ap[i + 1], wp[(size_t)(i + 1) * Cn], a1);
    a2 = fmaf(ap[i + 2], wp[(size_t)(i + 2) * Cn], a2);
    a3 = fmaf(ap[i + 3], wp[(size_t)(i + 3) * Cn], a3);
  }
  __shared__ float red[256];
  red[t] = (a0 + a1) + (a2 + a3);
  __syncthreads();
  const float v = red[cl] + red[cl + 64] + red[cl + 128] + red[cl + 192];
  if (dg == 0) {
    const int idx = blockIdx.y * 4096 + m * 64 + (cl ^ ((m & 7) << 3));
    const bf16 hi = __float2bfloat16(v);
    VgH[idx] = hi;
    VgL[idx] = __float2bfloat16(v - __bfloat162float(hi));
  }
  if (blockIdx.y == 0) {
    __syncthreads();
    red[t] = av[m * Dn + t] * bias[t] + av[m * Dn + t + 256] * bias[t + 256];
    __syncthreads();
    if (t < 64) {
      float s = red[t] + red[t + 64] + red[t + 128] + red[t + 192];
#pragma unroll
      for (int off = 32; off > 0; off >>= 1) s += __shfl_down(s, off);
      if (t == 0) c0[m] = s;
    }
  }
}

// ---------------------------------------------------------------------------
// K1: logits[b][m][n] = x[b][n][:].V[m][:] + c0[m]
// V (hi+lo) staged by global_load_lds dwordx4 (pre-swizzled source, linear
// LDS dest), double-buffered 64-k chunks, 1 barrier/chunk.  Reads swizzled
// -> conflict-free b128.  x in registers (coalesced rows), 2-chunk prefetch.
// LDS 32KB.  grid (Nn/64, Bn) = 512, block 256.
// ---------------------------------------------------------------------------
__global__ __launch_bounds__(256, 2) void logits_kernel(
    const float* __restrict__ x, const bf16* __restrict__ VgH,
    const bf16* __restrict__ VgL, const float* __restrict__ c0,
    float* __restrict__ logits) {
  const int n0 = blockIdx.x * 64;
  const int b = blockIdx.y;
  const int t = threadIdx.x;
  __shared__ short VsH[2][4096];
  __shared__ short VsL[2][4096];
  const int w = t >> 6, lane = t & 63, lr = lane & 15, q = lane >> 4;

  const float* xrow = x + (size_t)(b * Nn + n0 + w * 16 + lr) * Cn + q * 8;

  f32x4 acc[4];
#pragma unroll
  for (int i = 0; i < 4; ++i) acc[i] = (f32x4){0.f, 0.f, 0.f, 0.f};

  // --- stage V chunk 0 into buf 0 (async) ---
#pragma unroll
  for (int r = 0; r < 2; ++r) {
    const int off = (w + 4 * r) * 512;
    gl_lds16(VgH + off + lane * 8, &VsH[0][off]);
    gl_lds16(VgL + off + lane * 8, &VsL[0][off]);
  }

  // --- x register prefetch, 2 chunks (128 k) deep ---
  float4 xa0[2], xa1[2], xb0[2], xb1[2], xc0[2], xc1[2];
#pragma unroll
  for (int s = 0; s < 2; ++s) {
    xa0[s] = *(const float4*)(xrow + s * 32);
    xa1[s] = *(const float4*)(xrow + s * 32 + 4);
    xb0[s] = *(const float4*)(xrow + 64 + s * 32);
    xb1[s] = *(const float4*)(xrow + 64 + s * 32 + 4);
    xc0[s] = xb0[s]; xc1[s] = xb1[s];
  }

  const int rsw = (lr & 7) << 3;  // V-row swizzle (row&7 == lr&7 for all mt)
  int cur = 0;
  for (int ck = 0; ck < 16; ++ck, cur ^= 1) {
    __syncthreads();  // buf[cur] landed (barrier drains vmcnt); prev reads done
    if (ck + 1 < 16) {  // async-stage next chunk into other buffer
#pragma unroll
      for (int r = 0; r < 2; ++r) {
        const int off = (w + 4 * r) * 512;
        gl_lds16(VgH + (ck + 1) * 4096 + off + lane * 8, &VsH[cur ^ 1][off]);
        gl_lds16(VgL + (ck + 1) * 4096 + off + lane * 8, &VsL[cur ^ 1][off]);
      }
    }
    const int kc = ck * 64;
    if (kc + 128 < Cn) {  // x chunk kc+128 into regs
#pragma unroll
      for (int s = 0; s < 2; ++s) {
        xc0[s] = *(const float4*)(xrow + kc + 128 + s * 32);
        xc1[s] = *(const float4*)(xrow + kc + 128 + s * 32 + 4);
      }
    }
#pragma unroll
    for (int s = 0; s < 2; ++s) {
      short8 a;
      a[0] = bfbits(xa0[s].x); a[1] = bfbits(xa0[s].y);
      a[2] = bfbits(xa0[s].z); a[3] = bfbits(xa0[s].w);
      a[4] = bfbits(xa1[s].x); a[5] = bfbits(xa1[s].y);
      a[6] = bfbits(xa1[s].z); a[7] = bfbits(xa1[s].w);
      const int kx = (s * 32 + q * 8) ^ rsw;
#pragma unroll
      for (int mt = 0; mt < 4; ++mt) {
        const int idx = (mt * 16 + lr) * 64 + kx;
        acc[mt] = MFMA16(a, *(const short8*)&VsH[cur][idx], acc[mt]);
        acc[mt] = MFMA16(a, *(const short8*)&VsL[cur][idx], acc[mt]);
      }
    }
#pragma unroll
    for (int s = 0; s < 2; ++s) {  // rotate x pipeline
      xa0[s] = xb0[s]; xa1[s] = xb1[s];
      xb0[s] = xc0[s]; xb1[s] = xc1[s];
    }
  }
  // D layout: row(n)=q*4+reg, col(m)=lr  [m89-verified]
#pragma unroll
  for (int mt = 0; mt < 4; ++mt) {
    const int m = mt * 16 + lr;
    const float bb = c0[m];
    float4 o;
    o.x = acc[mt][0] + bb; o.y = acc[mt][1] + bb;
    o.z = acc[mt][2] + bb; o.w = acc[mt][3] + bb;
    *(float4*)&logits[(size_t)(b * Mn + m) * Nn + n0 + w * 16 + q * 4] = o;
  }
}

// ---------------------------------------------------------------------------
// K2: softmax over N per (b,m) row.  Weights written in pool's swizzled LDS
// image: tile (b, c128=n>>7) of [64 m][128 kk], short idx =
// (b*32+c128)*8192 + m*128 + ((n&127) ^ ((m&7)<<4)).  grid Bn*Mn, block 256.
// ---------------------------------------------------------------------------
__global__ __launch_bounds__(256) void softmax_kernel(
    const float* __restrict__ logits, bf16* __restrict__ wgt) {
  const int row = blockIdx.x;  // b*Mn + m
  const int b = row >> 6, m = row & 63;
  const int t = threadIdx.x;
  const float* L = logits + (size_t)row * Nn;
  float v[16];
  float mx = -3.4e38f;
#pragma unroll
  for (int i = 0; i < 16; ++i) {
    v[i] = L[t + 256 * i];
    mx = fmaxf(mx, v[i]);
  }
#pragma unroll
  for (int off = 32; off > 0; off >>= 1) mx = fmaxf(mx, __shfl_down(mx, off));
  __shared__ float sred[4];
  if ((t & 63) == 0) sred[t >> 6] = mx;
  __syncthreads();
  mx = fmaxf(fmaxf(sred[0], sred[1]), fmaxf(sred[2], sred[3]));
  float sum = 0.f;
#pragma unroll
  for (int i = 0; i < 16; ++i) {
    v[i] = __expf(v[i] - mx);
    sum += v[i];
  }
#pragma unroll
  for (int off = 32; off > 0; off >>= 1) sum += __shfl_down(sum, off);
  __syncthreads();
  if ((t & 63) == 0) sred[t >> 6] = sum;
  __syncthreads();
  const float inv = 1.f / (sred[0] + sred[1] + sred[2] + sred[3]);
  const int msw = (m & 7) << 4;
#pragma unroll
  for (int i = 0; i < 16; ++i) {
    const int n = t + 256 * i;
    const int idx = (b * 32 + (n >> 7)) * 8192 + m * 128 + ((n & 127) ^ msw);
    wgt[idx] = __float2bfloat16(v[i] * inv);
  }
}

// ---------------------------------------------------------------------------
// K3: part[ks][b][m][c] = sum_{k-quarter} wgt[b][m][k]*x[b][k][c]
// wgt staged via global_load_lds (pre-swizzled tiles, linear dest); XT
// unpadded + XOR-swizzled (write 2-way = free, read conflict-free).  Both
// double-buffered, ONE barrier per 128-k chunk.  LDS 64KB -> 2 blocks/CU,
// grid (Cn/64, Bn, 4) = 512 = 2/CU (matched).  block 256.
// ---------------------------------------------------------------------------
__global__ __launch_bounds__(256, 2) void pool_kernel(
    const float* __restrict__ x, const bf16* __restrict__ wgt,
    float* __restrict__ part) {
  const int cbase = blockIdx.x * 64;
  const int b = blockIdx.y;
  const int ks = blockIdx.z;
  const int t = threadIdx.x;
  __shared__ short XT[2][64][128];  // [buf][c][k ^ ((c&7)<<4)]
  __shared__ short Ws[2][8192];     // [buf][m*128 + (kk ^ ((m&7)<<4))]
  const int w = t >> 6, lane = t & 63, lr = lane & 15, q = lane >> 4;
  const int mh = (w & 1) * 32, ch = (w >> 1) * 32;
  f32x4 acc[2][2];
#pragma unroll
  for (int i = 0; i < 2; ++i)
#pragma unroll
    for (int j = 0; j < 2; ++j) acc[i][j] = (f32x4){0.f, 0.f, 0.f, 0.f};

  const int h = t & 15, g = t >> 4;
  const int hb = 4 * (h & 1);      // (4h+j)&7 = hb + j
  const int NQ = Nn / 4;
  const int kbase = ks * NQ;
  const int tile0 = b * 32 + ks * 8;  // first c128-tile of this quarter
  const float* xsrc = x + (size_t)b * Nn * Cn + (size_t)(kbase + 4 * g) * Cn + cbase + 4 * h;

  // --- stage Ws chunk 0 (async) ---
#pragma unroll
  for (int r = 0; r < 4; ++r) {
    const int off = (w + 4 * r) * 512;
    gl_lds16(wgt + (size_t)tile0 * 8192 + off + lane * 8, &Ws[0][off]);
  }

  float4 pf[8];
#pragma unroll
  for (int i = 0; i < 4; ++i) {  // x chunk 0
    pf[i]     = *(const float4*)(xsrc + (size_t)i * Cn);
    pf[4 + i] = *(const float4*)(xsrc + (size_t)(64 + i) * Cn);
  }
  // stage x chunk 0 into XT[0]
#pragma unroll
  for (int blk = 0; blk < 2; ++blk) {
    const float4 r0 = pf[blk * 4 + 0], r1 = pf[blk * 4 + 1];
    const float4 r2 = pf[blk * 4 + 2], r3 = pf[blk * 4 + 3];
    const int kb2 = blk * 64 + 4 * g;
    short4x v0, v1, v2, v3;
    v0[0] = bfbits(r0.x); v0[1] = bfbits(r1.x); v0[2] = bfbits(r2.x); v0[3] = bfbits(r3.x);
    v1[0] = bfbits(r0.y); v1[1] = bfbits(r1.y); v1[2] = bfbits(r2.y); v1[3] = bfbits(r3.y);
    v2[0] = bfbits(r0.z); v2[1] = bfbits(r1.z); v2[2] = bfbits(r2.z); v2[3] = bfbits(r3.z);
    v3[0] = bfbits(r0.w); v3[1] = bfbits(r1.w); v3[2] = bfbits(r2.w); v3[3] = bfbits(r3.w);
    *(short4x*)&XT[0][4 * h + 0][kb2 ^ ((hb + 0) << 4)] = v0;
    *(short4x*)&XT[0][4 * h + 1][kb2 ^ ((hb + 1) << 4)] = v1;
    *(short4x*)&XT[0][4 * h + 2][kb2 ^ ((hb + 2) << 4)] = v2;
    *(short4x*)&XT[0][4 * h + 3][kb2 ^ ((hb + 3) << 4)] = v3;
  }
#pragma unroll
  for (int i = 0; i < 4; ++i) {  // x chunk 1 prefetch
    pf[i]     = *(const float4*)(xsrc + (size_t)(128 + i) * Cn);
    pf[4 + i] = *(const float4*)(xsrc + (size_t)(192 + i) * Cn);
  }

  const int asw = (lr & 7) << 4;  // shared by A and B reads (rows ±32 keep &7)
  int cur = 0;
  for (int kc = 0; kc < NQ; kc += 128, cur ^= 1) {
    __syncthreads();  // XT[cur], Ws[cur] ready; prev buffer reads done
    if (kc + 128 < NQ) {
      // async-stage next wgt chunk
#pragma unroll
      for (int r = 0; r < 4; ++r) {
        const int off = (w + 4 * r) * 512;
        gl_lds16(wgt + (size_t)(tile0 + (kc >> 7) + 1) * 8192 + off + lane * 8,
                 &Ws[cur ^ 1][off]);
      }
      // stage x chunk kc+128 into XT[cur^1]
#pragma unroll
      for (int blk = 0; blk < 2; ++blk) {
        const float4 r0 = pf[blk * 4 + 0], r1 = pf[blk * 4 + 1];
        const float4 r2 = pf[blk * 4 + 2], r3 = pf[blk * 4 + 3];
        const int kb2 = blk * 64 + 4 * g;
        short4x v0, v1, v2, v3;
        v0[0] = bfbits(r0.x); v0[1] = bfbits(r1.x); v0[2] = bfbits(r2.x); v0[3] = bfbits(r3.x);
        v1[0] = bfbits(r0.y); v1[1] = bfbits(r1.y); v1[2] = bfbits(r2.y); v1[3] = bfbits(r3.y);
        v2[0] = bfbits(r0.z); v2[1] = bfbits(r1.z); v2[2] = bfbits(r2.z); v2[3] = bfbits(r3.z);
        v3[0] = bfbits(r0.w); v3[1] = bfbits(r1.w); v3[2] = bfbits(r2.w); v3[3] = bfbits(r3.w);
        *(short4x*)&XT[cur ^ 1][4 * h + 0][kb2 ^ ((hb + 0) << 4)] = v0;
        *(short4x*)&XT[cur ^ 1][4 * h + 1][kb2 ^ ((hb + 1) << 4)] = v1;
        *(short4x*)&XT[cur ^ 1][4 * h + 2][kb2 ^ ((hb + 2) << 4)] = v2;
        *(short4x*)&XT[cur ^ 1][4 * h + 3][kb2 ^ ((hb + 3) << 4)] = v3;
      }
      if (kc + 256 < NQ) {  // prefetch x chunk kc+256
#pragma unroll
        for (int i = 0; i < 4; ++i) {
          pf[i]     = *(const float4*)(xsrc + (size_t)(kc + 256 + i) * Cn);
          pf[4 + i] = *(const float4*)(xsrc + (size_t)(kc + 320 + i) * Cn);
        }
      }
    }
#pragma unroll
    for (int kk = 0; kk < 128; kk += 32) {
      const int kx = (kk + q * 8) ^ asw;
      const short8 a0 = *(const short8*)&Ws[cur][(mh + lr) * 128 + kx];
      const short8 a1 = *(const short8*)&Ws[cur][(mh + 16 + lr) * 128 + kx];
      const short8 b0 = *(const short8*)&XT[cur][ch + lr][kx];
      const short8 b1 = *(const short8*)&XT[cur][ch + 16 + lr][kx];
      acc[0][0] = MFMA16(a0, b0, acc[0][0]);
      acc[0][1] = MFMA16(a0, b1, acc[0][1]);
      acc[1][0] = MFMA16(a1, b0, acc[1][0]);
      acc[1][1] = MFMA16(a1, b1, acc[1][1]);
    }
  }
  float* pout = part + ((size_t)ks * Bn + b) * Mn * Cn;
#pragma unroll
  for (int mi = 0; mi < 2; ++mi)
#pragma unroll
    for (int ci = 0; ci < 2; ++ci) {
      const int m = mh + mi * 16 + q * 4;
      const int c = cbase + ch + ci * 16 + lr;
#pragma unroll
      for (int reg = 0; reg < 4; ++reg)
        pout[(size_t)(m + reg) * Cn + c] = acc[mi][ci][reg];
    }
}

// ---------------------------------------------------------------------------
// K4: out = sum of 4 partials (float4).  grid 512, block 256
// ---------------------------------------------------------------------------
__global__ __launch_bounds__(256) void reduce_kernel(
    const float* __restrict__ part, float* __restrict__ out) {
  const int i = blockIdx.x * 256 + threadIdx.x;
  const float4* p = (const float4*)part;
  const int S4 = (Bn * Mn * Cn) / 4;
  float4 o = (float4){0.f, 0.f, 0.f, 0.f};
#pragma unroll
  for (int j = 0; j < 4; ++j) {
    const float4 v = p[i + j * S4];
    o.x += v.x; o.y += v.y; o.z += v.z; o.w += v.w;
  }
  ((float4*)out)[i] = o;
}

extern "C" void kernel_launch(void* const* d_in, const int* in_sizes, int n_in,
                              void* d_out, int out_size, void* d_ws, size_t ws_size,
                              hipStream_t stream) {
  const float* x = (const float*)d_in[0];
  const float* W = (const float*)d_in[1];
  const float* bias = (const float*)d_in[2];
  const float* av = (const float*)d_in[3];
  float* out = (float*)d_out;
  char* ws = (char*)d_ws;

  bf16* VgH = (bf16*)(ws + 0);           // 131072 B (swizzled V-hi tiles)
  bf16* VgL = (bf16*)(ws + 131072);      // 131072 B (swizzled V-lo tiles)
  float* c0 = (float*)(ws + 262144);     // 1024 B
  bf16* wgt = (bf16*)(ws + 263168);      // 4194304 B (swizzled wgt tiles)
  // logits (live K1->K2) and part (live K3->K4) time-share one 8.4MB region
  float* logits = (float*)(ws + 4457472);  // 8388608 B
  float* part = (float*)(ws + 4457472);    // 4 x 2097152 B  (total ~12.8 MB)

  prep_kernel<<<dim3(Mn, Cn / 64), 256, 0, stream>>>(W, bias, av, VgH, VgL, c0);
  logits_kernel<<<dim3(Nn / 64, Bn), 256, 0, stream>>>(x, VgH, VgL, c0, logits);
  softmax_kernel<<<Bn * Mn, 256, 0, stream>>>(logits, wgt);
  pool_kernel<<<dim3(Cn / 64, Bn, 4), 256, 0, stream>>>(x, wgt, part);
  reduce_kernel<<<(Bn * Mn * Cn) / 1024, 256, 0, stream>>>(part, out);
}